// Round 1
// baseline (545.275 us; speedup 1.0000x reference)
//
#include <hip/hip_runtime.h>
#include <math.h>

#define BATCH 2048
#define IN_F 256
#define OUT_F 256
#define DEG 8

typedef __attribute__((ext_vector_type(4))) float f4;

// ---------- workspace layout (floats) ----------
// ws[0..63]   : per-block partial mins
// ws[64..127] : per-block partial maxs
// ws[128]     : a  (scale:  xs = a*x + c)
// ws[129]     : c  (offset: c = -a*xmin - 1)
// ws[256 ..]  : base_out (2048 x 256 fp32 = 2 MB)

// ---------------- min/max over whole x tensor ----------------
__global__ __launch_bounds__(256) void k_minmax_partial(const float* __restrict__ x,
                                                        float* __restrict__ ws) {
    int t = threadIdx.x;
    int blk = blockIdx.x;          // 64 blocks
    const f4* x4 = (const f4*)x;   // 131072 float4 total; 2048/block; 8/thread
    float mn = 1e30f, mx = -1e30f;
    int base = blk * 2048 + t;
#pragma unroll
    for (int j = 0; j < 8; ++j) {
        f4 v = x4[base + j * 256];
        mn = fminf(mn, fminf(fminf(v.x, v.y), fminf(v.z, v.w)));
        mx = fmaxf(mx, fmaxf(fmaxf(v.x, v.y), fmaxf(v.z, v.w)));
    }
#pragma unroll
    for (int off = 32; off > 0; off >>= 1) {
        mn = fminf(mn, __shfl_down(mn, off));
        mx = fmaxf(mx, __shfl_down(mx, off));
    }
    __shared__ float smn[4], smx[4];
    if ((t & 63) == 0) { smn[t >> 6] = mn; smx[t >> 6] = mx; }
    __syncthreads();
    if (t == 0) {
        mn = fminf(fminf(smn[0], smn[1]), fminf(smn[2], smn[3]));
        mx = fmaxf(fmaxf(smx[0], smx[1]), fmaxf(smx[2], smx[3]));
        ws[blk] = mn;
        ws[64 + blk] = mx;
    }
}

__global__ void k_minmax_final(float* __restrict__ ws) {
    int t = threadIdx.x;  // 64 threads, 1 wave
    float mn = ws[t], mx = ws[64 + t];
#pragma unroll
    for (int off = 32; off > 0; off >>= 1) {
        mn = fminf(mn, __shfl_down(mn, off));
        mx = fmaxf(mx, __shfl_down(mx, off));
    }
    if (t == 0) {
        float a = 2.0f / (mx - mn);
        ws[128] = a;
        ws[129] = -a * mn - 1.0f;
    }
}

// ---------------- base_out = swish(x) @ base_weight ----------------
// grid (64, 4): 32-batch x 64-out tile per block, 256 threads, 2x4 per thread.
#define KC 64
__global__ __launch_bounds__(256) void k_base(const float* __restrict__ x,
                                              const float* __restrict__ w,
                                              float* __restrict__ basews) {
    __shared__ float As[32][KC + 1];   // +1 pad breaks bank conflicts
    __shared__ float Bs[KC][64];
    int t = threadIdx.x;
    int b0 = blockIdx.x * 32;
    int o0 = blockIdx.y * 64;
    int to = t & 15;   // o quad: o = o0 + to*4 .. +3
    int tb = t >> 4;   // b pair: b = b0 + 2*tb, +1
    f4 acc0 = {0.f, 0.f, 0.f, 0.f}, acc1 = {0.f, 0.f, 0.f, 0.f};
    for (int kc = 0; kc < IN_F; kc += KC) {
        __syncthreads();
        // A tile: 32 x 64, swish applied on load. 512 float4, 2/thread.
#pragma unroll
        for (int j = 0; j < 2; ++j) {
            int e = t + 256 * j;
            int b = e >> 4;
            int k4 = e & 15;
            f4 v = ((const f4*)(x + (size_t)(b0 + b) * IN_F + kc))[k4];
            v.x = v.x / (1.0f + __expf(-v.x));
            v.y = v.y / (1.0f + __expf(-v.y));
            v.z = v.z / (1.0f + __expf(-v.z));
            v.w = v.w / (1.0f + __expf(-v.w));
            As[b][k4 * 4 + 0] = v.x;
            As[b][k4 * 4 + 1] = v.y;
            As[b][k4 * 4 + 2] = v.z;
            As[b][k4 * 4 + 3] = v.w;
        }
        // B tile: 64 x 64. 1024 float4, 4/thread.
#pragma unroll
        for (int j = 0; j < 4; ++j) {
            int e = t + 256 * j;
            int k = e >> 4;
            int o4 = e & 15;
            f4 v = ((const f4*)(w + (size_t)(kc + k) * OUT_F + o0))[o4];
            *((f4*)&Bs[k][o4 * 4]) = v;
        }
        __syncthreads();
#pragma unroll 8
        for (int k = 0; k < KC; ++k) {
            float a0 = As[2 * tb][k];      // broadcast across 16 lanes
            float a1 = As[2 * tb + 1][k];
            f4 bv = *((const f4*)&Bs[k][to * 4]);
            acc0 += a0 * bv;
            acc1 += a1 * bv;
        }
    }
    float* dst = basews + (size_t)(b0 + 2 * tb) * OUT_F + o0 + to * 4;
    *((f4*)dst) = acc0;
    *((f4*)(dst + OUT_F)) = acc1;
}

// ---------------- main: out[b][i][o] = base[b][o] + sum_d T_d(xs[b][i]) * cw[i][o][d] ----
// grid (IN_F/16, OUT_F/64, BATCH/32), 256 threads.
// Thread owns fixed (i, o-quad): cheb weights (32 floats) live in registers,
// reused across 32 batches. No LDS, no syncs in hot loop. Write-BW bound.
__global__ __launch_bounds__(256) void k_main(const float* __restrict__ x,
                                              const float* __restrict__ cw,
                                              const float* __restrict__ basews,
                                              const float* __restrict__ scl,
                                              float* __restrict__ out) {
    int t = threadIdx.x;
    int to = t & 15;   // o quad index
    int ig = t >> 4;   // i within tile (0..15)
    int i0 = blockIdx.x * 16;
    int o0 = blockIdx.y * 64;
    int b0 = blockIdx.z * 32;
    float a = scl[0];
    float c = scl[1];
    int i = i0 + ig;

    // cw[i][o][d], d innermost: this thread's (i, o-quad) slice is 32
    // consecutive floats -> 8 coalesced float4 loads, once per 32 batches.
    const f4* wsrc = (const f4*)(cw + ((size_t)i * OUT_F + (o0 + to * 4)) * DEG);
    float wv[4][8];  // [o_local][d] -> fully unrolled, stays in VGPRs
#pragma unroll
    for (int ol = 0; ol < 4; ++ol) {
        f4 lo = wsrc[ol * 2];
        f4 hi = wsrc[ol * 2 + 1];
        wv[ol][0] = lo.x; wv[ol][1] = lo.y; wv[ol][2] = lo.z; wv[ol][3] = lo.w;
        wv[ol][4] = hi.x; wv[ol][5] = hi.y; wv[ol][6] = hi.z; wv[ol][7] = hi.w;
    }

    const float* xp = x + (size_t)b0 * IN_F + i;
    const float* bp = basews + (size_t)b0 * OUT_F + o0 + to * 4;
    float* op = out + ((size_t)b0 * IN_F + i) * OUT_F + o0 + to * 4;

    for (int bb = 0; bb < 32; ++bb) {
        float xv = xp[(size_t)bb * IN_F];
        float xs = fmaf(a, xv, c);
        float T[8];
        T[0] = 1.0f;
        T[1] = xs;
        float x2 = xs + xs;
#pragma unroll
        for (int d = 2; d < DEG; ++d) T[d] = fmaf(x2, T[d - 1], -T[d - 2]);

        f4 r = *(const f4*)(bp + (size_t)bb * OUT_F);
#pragma unroll
        for (int d = 0; d < DEG; ++d) {
            r.x = fmaf(T[d], wv[0][d], r.x);
            r.y = fmaf(T[d], wv[1][d], r.y);
            r.z = fmaf(T[d], wv[2][d], r.z);
            r.w = fmaf(T[d], wv[3][d], r.w);
        }
        __builtin_nontemporal_store(r, (f4*)(op + (size_t)bb * IN_F * OUT_F));
    }
}

extern "C" void kernel_launch(void* const* d_in, const int* in_sizes, int n_in,
                              void* d_out, int out_size, void* d_ws, size_t ws_size,
                              hipStream_t stream) {
    (void)in_sizes; (void)n_in; (void)out_size; (void)ws_size;
    const float* x  = (const float*)d_in[0];
    const float* bw = (const float*)d_in[1];
    const float* cw = (const float*)d_in[2];
    float* out = (float*)d_out;
    float* ws = (float*)d_ws;
    float* scl = ws + 128;
    float* basews = ws + 256;

    k_minmax_partial<<<64, 256, 0, stream>>>(x, ws);
    k_minmax_final<<<1, 64, 0, stream>>>(ws);
    dim3 gb(BATCH / 32, OUT_F / 64);
    k_base<<<gb, 256, 0, stream>>>(x, bw, basews);
    dim3 gm(IN_F / 16, OUT_F / 64, BATCH / 32);
    k_main<<<gm, 256, 0, stream>>>(x, cw, basews, scl, out);
}